// Round 2
// 892.486 us; speedup vs baseline: 1.0338x; 1.0338x over previous
//
#include <hip/hip_runtime.h>
#include <cmath>

#define NN   1000
#define TT   4
#define PP   10
#define DD   13
#define FF   128
#define HH   128
#define EAA  16
#define KDIM 64
#define EE   20000
#define I_NODE 91
#define I_EDGE 169
#define MROW  13000            // N*D
#define OUT_FLOAT4 42250000L   // 13000*13000/4

// ---------------- K0: zero exactly the 676MB validated output region --------
__global__ __launch_bounds__(256) void k_zero(float4* __restrict__ p, long n4) {
  long i = (long)blockIdx.x * 256 + threadIdx.x;
  if (i < n4) p[i] = make_float4(0.f, 0.f, 0.f, 0.f);
}

// ---------------- Kc1: Wcomb[p] = W_edge[p] @ cob_edge[p]  ([10][64][169]) --
__global__ __launch_bounds__(192) void k_comb_edge(
    const float* __restrict__ We, const float* __restrict__ cob,
    float* __restrict__ Wcomb) {
  int pk = blockIdx.x;            // p*64 + k
  int p = pk >> 6;
  int t = threadIdx.x;
  if (t >= I_EDGE) return;
  float acc = 0.f;
  const float* wrow = We + pk * I_EDGE;              // W_edge[p][k][:]
  const float* crow = cob + p * I_EDGE * I_EDGE + t; // cob[p][:][t]
  for (int i = 0; i < I_EDGE; ++i) acc += wrow[i] * crow[i * I_EDGE];
  Wcomb[pk * I_EDGE + t] = acc;
}

// ---------------- Kc2: Wnc[t] = W_node[t] @ cob_node[t]  ([4][128][169]) ----
__global__ __launch_bounds__(192) void k_comb_node(
    const float* __restrict__ Wn, const float* __restrict__ cob,
    float* __restrict__ Wnc) {
  int tf = blockIdx.x;            // t*128 + f
  int ty = tf >> 7;
  int t = threadIdx.x;
  if (t >= I_EDGE) return;
  float acc = 0.f;
  const float* wrow = Wn + tf * I_NODE;
  const float* crow = cob + ty * I_NODE * I_EDGE + t;
  for (int i = 0; i < I_NODE; ++i) acc += wrow[i] * crow[i * I_EDGE];
  Wnc[tf * I_EDGE + t] = acc;
}

// ---------------- K1: m = node_feats @ W_msg ; zero agg ----------------
__global__ __launch_bounds__(128) void k_node_msg(
    const float* __restrict__ nf, const float* __restrict__ Wmsg,
    float* __restrict__ m, float* __restrict__ agg) {
  int n = blockIdx.x, j = threadIdx.x;
  __shared__ float row[FF];
  row[j] = nf[n * FF + j];
  __syncthreads();
  float acc = 0.f;
#pragma unroll 8
  for (int f = 0; f < FF; ++f) acc += row[f] * Wmsg[f * FF + j];
  m[n * FF + j] = acc;
  agg[n * FF + j] = 0.f;
}

// ---------------- K2: symmetric segment sum via atomics ----------------
__global__ __launch_bounds__(256) void k_scatter(
    const float* __restrict__ m, const int* __restrict__ src,
    const int* __restrict__ dst, float* __restrict__ agg) {
  int idx = blockIdx.x * 256 + threadIdx.x;
  if (idx >= EE * FF) return;
  int e = idx >> 7, j = idx & 127;
  int s = src[e], d = dst[e];
  atomicAdd(&agg[d * FF + j], m[s * FF + j]);
  atomicAdd(&agg[s * FF + j], m[d * FF + j]);
}

// ---------------- K3: node_h ----------------
__global__ __launch_bounds__(128) void k_node_h(
    const float* __restrict__ nf, const float* __restrict__ agg,
    const float* __restrict__ na, const float* __restrict__ Wattr,
    float* __restrict__ nh) {
  int n = blockIdx.x, j = threadIdx.x;
  float a = 0.f;
#pragma unroll
  for (int t = 0; t < TT; ++t) a += na[n * TT + t] * Wattr[t * FF + j];
  nh[n * FF + j] = nf[n * FF + j] + agg[n * FF + j] * (1.0f / 20.0f) + a;
}

// ---------------- K3b: per-node precomputes (N=1000 << E=20000) -------------
// V1[n][j] = nh[n] @ Wem[0:128]   (src slot of edge-msg input)
// V2[n][j] = nh[n] @ Wem[128:256] (dst slot)
// U[n][k]      = nh[n] @ Wproj[128:256]  (slot-1 of edge op)
// U[n][64+k]   = nh[n] @ Wproj[256:384]  (slot-2 of edge op)
__global__ __launch_bounds__(128) void k_node_pre(
    const float* __restrict__ nh, const float* __restrict__ Wem,
    const float* __restrict__ Wproj, float* __restrict__ V1,
    float* __restrict__ V2, float* __restrict__ U) {
  int n = blockIdx.x, t = threadIdx.x;
  __shared__ float row[FF];
  row[t] = nh[n * FF + t];
  __syncthreads();
  float v1 = 0.f, v2 = 0.f;
#pragma unroll 4
  for (int f = 0; f < FF; ++f) {
    float x = row[f];
    v1 += x * Wem[f * HH + t];
    v2 += x * Wem[(FF + f) * HH + t];
  }
  V1[n * HH + t] = v1;
  V2[n * HH + t] = v2;
  int k = t & 63, half = t >> 6;
  const float* W = Wproj + (FF + half * FF) * KDIM + k;
  float u = 0.f;
#pragma unroll 4
  for (int f = 0; f < FF; ++f) u += row[f] * W[f * KDIM];
  U[n * 128 + t] = u;
}

// ---------------- K4: fused edge message + msg-projection -------------------
// em = tanh(V1[s] + V2[d] + [ef,ea] @ Wem[256:288]); hmsg = em @ Wproj[0:128]
#define EPB 8
__global__ __launch_bounds__(128) void k_edge_msg(
    const float* __restrict__ V1, const float* __restrict__ V2,
    const float* __restrict__ ef, const float* __restrict__ ea,
    const int* __restrict__ src, const int* __restrict__ dst,
    const float* __restrict__ Wem, const float* __restrict__ Wproj,
    float* __restrict__ hmsg) {
  int e0 = blockIdx.x * EPB;
  int j = threadIdx.x;
  __shared__ float efa[EPB][32];
  __shared__ float em[EPB][HH];
  for (int i = j; i < EPB * 32; i += 128) {
    int e = i >> 5, c = i & 31;
    efa[e][c] = (c < 16) ? ef[(e0 + e) * EAA + c] : ea[(e0 + e) * EAA + (c - 16)];
  }
  __syncthreads();
  // column j of the 32 ef/ea rows of Wem, reused across all 8 edges
  float wcol[32];
#pragma unroll
  for (int c = 0; c < 32; ++c) wcol[c] = Wem[(256 + c) * HH + j];
#pragma unroll
  for (int e = 0; e < EPB; ++e) {
    int s = src[e0 + e], d = dst[e0 + e];
    float acc = V1[s * HH + j] + V2[d * HH + j];
#pragma unroll
    for (int c = 0; c < 32; ++c) acc += efa[e][c] * wcol[c];
    em[e][j] = tanhf(acc);
  }
  __syncthreads();
  // hmsg[e][k] = sum_f em[e][f] * Wproj[f][k]   (rows 0..127 of Wproj)
  int k = j & 63, half = j >> 6;   // half -> edges {half, half+2, half+4, half+6}
  float a0 = 0.f, a1 = 0.f, a2 = 0.f, a3 = 0.f;
  for (int f = 0; f < HH; f += 4) {
    float4 m0 = *(const float4*)&em[half + 0][f];
    float4 m1 = *(const float4*)&em[half + 2][f];
    float4 m2 = *(const float4*)&em[half + 4][f];
    float4 m3 = *(const float4*)&em[half + 6][f];
    float w0 = Wproj[(f + 0) * KDIM + k], w1 = Wproj[(f + 1) * KDIM + k];
    float w2 = Wproj[(f + 2) * KDIM + k], w3 = Wproj[(f + 3) * KDIM + k];
    a0 += m0.x * w0 + m0.y * w1 + m0.z * w2 + m0.w * w3;
    a1 += m1.x * w0 + m1.y * w1 + m1.z * w2 + m1.w * w3;
    a2 += m2.x * w0 + m2.y * w1 + m2.z * w2 + m2.w * w3;
    a3 += m3.x * w0 + m3.y * w1 + m3.z * w2 + m3.w * w3;
  }
  hmsg[(e0 + half + 0) * KDIM + k] = a0;
  hmsg[(e0 + half + 2) * KDIM + k] = a1;
  hmsg[(e0 + half + 4) * KDIM + k] = a2;
  hmsg[(e0 + half + 6) * KDIM + k] = a3;
}

// ---------------- K5: node diagonal blocks (fused basis) ----------------
__global__ __launch_bounds__(192) void k_node_block(
    const float* __restrict__ nh, const int* __restrict__ ntype,
    const float* __restrict__ Wnc, float* __restrict__ M) {
  int n = blockIdx.x, t = threadIdx.x;
  int ty = ntype[n];
  __shared__ float row[FF];
  if (t < FF) row[t] = nh[n * FF + t];
  __syncthreads();
  if (t < I_EDGE) {
    float acc = 0.f;
    const float* W = Wnc + ty * FF * I_EDGE + t;
#pragma unroll 4
    for (int f = 0; f < FF; ++f) acc += row[f] * W[f * I_EDGE];
    int x = t / DD, y = t % DD;
    atomicAdd(&M[(size_t)(n * DD + x) * MROW + (n * DD + y)], acc);
  }
}

// ---------------- K6: edge blocks — h from precomputes, 4 edges/block -------
// h_ij = hmsg[e] + U[s][0:64] + U[d][64:128]; h_ji = hmsg[e] + U[d][0:64] + U[s][64:128]
#define EB2 4
__global__ __launch_bounds__(768) void k_edge_blk(
    const float* __restrict__ U, const float* __restrict__ hmsg,
    const int* __restrict__ src, const int* __restrict__ dst,
    const int* __restrict__ etype, const float* __restrict__ Wcomb,
    float* __restrict__ M) {
  int e0 = blockIdx.x * EB2;
  int t = threadIdx.x;      // 0..191
  int ei = threadIdx.y;     // 0..3
  int e = e0 + ei;
  __shared__ float h[EB2][2][KDIM];
  __shared__ float tji[EB2][I_EDGE];
  int s = src[e], d = dst[e], p = etype[e];
  if (t < 128) {
    int k = t & 63, w = t >> 6;      // w=0 -> ij, w=1 -> ji
    int a = w ? d : s, b = w ? s : d;
    h[ei][w][k] = hmsg[e * KDIM + k] + U[a * 128 + k] + U[b * 128 + 64 + k];
  }
  __syncthreads();
  float bij = 0.f, bji = 0.f;
  if (t < I_EDGE) {
    const float* W = Wcomb + p * KDIM * I_EDGE + t;
    for (int k = 0; k < KDIM; k += 4) {
      float4 hi = *(const float4*)&h[ei][0][k];
      float4 hj = *(const float4*)&h[ei][1][k];
      float w0 = W[(k + 0) * I_EDGE], w1 = W[(k + 1) * I_EDGE];
      float w2 = W[(k + 2) * I_EDGE], w3 = W[(k + 3) * I_EDGE];
      bij += hi.x * w0 + hi.y * w1 + hi.z * w2 + hi.w * w3;
      bji += hj.x * w0 + hj.y * w1 + hj.z * w2 + hj.w * w3;
    }
    tji[ei][t] = bji;
  }
  __syncthreads();
  if (t < I_EDGE) {
    int x = t / DD, y = t % DD;
    float eb = 0.5f * (bij + tji[ei][y * DD + x]);
    atomicAdd(&M[(size_t)(s * DD + x) * MROW + (d * DD + y)], eb);
    atomicAdd(&M[(size_t)(d * DD + y) * MROW + (s * DD + x)], eb);
  }
}

extern "C" void kernel_launch(void* const* d_in, const int* in_sizes, int n_in,
                              void* d_out, int out_size, void* d_ws, size_t ws_size,
                              hipStream_t stream) {
  const float* node_feats = (const float*)d_in[0];
  const float* node_attrs = (const float*)d_in[1];
  const float* edge_feats = (const float*)d_in[2];
  const float* edge_attrs = (const float*)d_in[3];
  const int*   edge_index = (const int*)d_in[4];
  const int*   node_types = (const int*)d_in[5];
  const int*   edge_types = (const int*)d_in[6];
  const float* W_msg  = (const float*)d_in[7];
  const float* W_attr = (const float*)d_in[8];
  const float* W_em   = (const float*)d_in[9];
  const float* W_proj = (const float*)d_in[10];
  const float* W_node = (const float*)d_in[11];
  const float* W_edge = (const float*)d_in[12];
  const float* cob_node = (const float*)d_in[13];
  const float* cob_edge = (const float*)d_in[14];

  float* M  = (float*)d_out;
  float* ws = (float*)d_ws;
  float* m_buf = ws;                  // N*F = 128000
  float* agg   = ws + 128000;         // N*F
  float* nh    = ws + 256000;         // N*F
  float* V1    = ws + 384000;         // N*H
  float* V2    = ws + 512000;         // N*H
  float* U     = ws + 640000;         // N*128
  float* hmsg  = ws + 768000;         // E*K = 1,280,000
  float* Wcomb = ws + 2048000;        // P*K*I_EDGE = 108,160
  float* Wnc   = ws + 2156160;        // T*F*I_EDGE = 86,528 (end ~9.0 MB)

  const int* src = edge_index;        // edge_index[0]
  const int* dst = edge_index + EE;   // edge_index[1]

  k_zero      <<<(int)((OUT_FLOAT4 + 255) / 256), 256, 0, stream>>>((float4*)M, OUT_FLOAT4);
  k_comb_edge <<<PP * KDIM, 192, 0, stream>>>(W_edge, cob_edge, Wcomb);
  k_comb_node <<<TT * FF, 192, 0, stream>>>(W_node, cob_node, Wnc);
  k_node_msg  <<<NN, 128, 0, stream>>>(node_feats, W_msg, m_buf, agg);
  k_scatter   <<<(EE * FF) / 256, 256, 0, stream>>>(m_buf, src, dst, agg);
  k_node_h    <<<NN, 128, 0, stream>>>(node_feats, agg, node_attrs, W_attr, nh);
  k_node_pre  <<<NN, 128, 0, stream>>>(nh, W_em, W_proj, V1, V2, U);
  k_edge_msg  <<<EE / EPB, 128, 0, stream>>>(V1, V2, edge_feats, edge_attrs, src, dst,
                                             W_em, W_proj, hmsg);
  k_node_block<<<NN, 192, 0, stream>>>(nh, node_types, Wnc, M);
  k_edge_blk  <<<dim3(EE / EB2), dim3(192, 4), 0, stream>>>(U, hmsg, src, dst, edge_types,
                                                            Wcomb, M);
}